// Round 5
// baseline (245.460 us; speedup 1.0000x reference)
//
#include <hip/hip_runtime.h>
#include <hip/hip_bf16.h>

// LowRankBilinearFusion on MI355X (gfx950) — v5
//
//  v4 + operand-swapped MFMA in bilinear so D-rows = f (quad*4+reg), D-cols = n
//  (l15). Each acc floatx4 then holds 4 CONSECUTIVE f values -> epilogue does
//  float4 bias add + relu + global_store_dwordx4 (16 stores/thread vs 64).
//  Theory: v3/v4 bilinear was store-issue-bound (33.5M scalar dword stores
//  ~54 us of VMEM issue); 4x fewer store instrs -> write-BW bound (~21 us).
//
//  1. proj: up_f32 = u @ Wu^T (1024x256, D=1024); vp_bf = v @ Wv^T (4096x256,
//     D=2048); + Wp fp32 -> bf16 convert (blocks 0..31). Unchanged from v4.
//  2. bilinear: o = relu( (vp[b] (.) up[bm]) @ Wp^T + bp ), barrier-free K-loop,
//     A' in LDS (XOR-swizzled), B = static bf16 Wp from L2 (reg dbuf).

typedef __attribute__((ext_vector_type(8))) short short8;
typedef __attribute__((ext_vector_type(4))) float floatx4;
typedef __attribute__((ext_vector_type(4))) unsigned uintx4;

__device__ __forceinline__ short f2bf(float f) {
    union { float f; unsigned u; } cv; cv.f = f;
    unsigned r = cv.u + 0x7fffu + ((cv.u >> 16) & 1u);
    return (short)(r >> 16);
}
// RNE pack of two fp32 into one dword of two bf16 (lo = x, hi = y).
__device__ __forceinline__ unsigned pack_rne(float x, float y) {
    __hip_bfloat162 h = __float22bfloat162_rn(make_float2(x, y));
    union { __hip_bfloat162 h; unsigned u; } cv; cv.h = h;
    return cv.u;
}
// (bf16 a)*ua, (bf16 b)*ub -> packed bf16 pair, RNE.
__device__ __forceinline__ unsigned scale2_rne(short a, short b, float ua, float ub) {
    float x = __uint_as_float(((unsigned)(unsigned short)a) << 16) * ua;
    float y = __uint_as_float(((unsigned)(unsigned short)b) << 16) * ub;
    return pack_rne(x, y);
}

#define MFMA16(a, b, c) __builtin_amdgcn_mfma_f32_16x16x32_bf16((a), (b), (c), 0, 0, 0)

// ---------------------------------------------------------------------------
// proj: 32x64 tiles. pidx 0..31 -> u (D=1024), 32..159 -> v (D=2048).
// 256 threads = 4 waves (2x2), wave tile 16x32. K-chunk 64. (v3/v4 structure)
// Blocks 0..31 additionally convert Wp fp32 -> bf16 (8 elems/thread).
// ---------------------------------------------------------------------------
__global__ __launch_bounds__(256) void proj_kernel(
    const float* __restrict__ u, const float* __restrict__ Wu,
    float* __restrict__ upf,
    const float* __restrict__ v, const float* __restrict__ Wv,
    short* __restrict__ vpb,
    const float* __restrict__ Wp, short* __restrict__ Wp_bf)
{
    __shared__ __align__(16) short Xs[2][32 * 64];    // 4 KB each
    __shared__ __align__(16) short Wsh[2][64 * 64];   // 8 KB each

    const int tid  = threadIdx.x;
    const int lane = tid & 63;
    const int wave = tid >> 6;
    const int quad = lane >> 4;
    const int l15  = lane & 15;

    const int bid = blockIdx.x;

    // Wp fp32 -> bf16 (65536 elems over blocks 0..31)
    if (bid < 32) {
        const int widx = (bid * 256 + tid) * 8;
        float4 g0 = *(const float4*)(Wp + widx);
        float4 g1 = *(const float4*)(Wp + widx + 4);
        short8 o;
        o[0] = f2bf(g0.x); o[1] = f2bf(g0.y); o[2] = f2bf(g0.z); o[3] = f2bf(g0.w);
        o[4] = f2bf(g1.x); o[5] = f2bf(g1.y); o[6] = f2bf(g1.z); o[7] = f2bf(g1.w);
        *(short8*)(Wp_bf + widx) = o;
    }

    // bid -> (pidx, cb): 4 cb-blocks of a panel share an XCD (bid%8 const).
    const int xcd = bid & 7, j = bid >> 3;
    const int cb  = j & 3;
    const int pidx = xcd + 8 * (j >> 2);              // 0..159
    const float *X, *W; int D, r0; bool is_u;
    if (pidx < 32) { is_u = true;  X = u; W = Wu; D = 1024; r0 = pidx * 32; }
    else           { is_u = false; X = v; W = Wv; D = 2048; r0 = (pidx - 32) * 32; }
    const int c0 = cb * 64;
    const int wr = (wave >> 1) * 16;                  // 0,16
    const int wc = (wave & 1) * 32;                   // 0,32

    const int xr_ = tid >> 3, xk = (tid & 7) * 8;
    const int wr_ = tid >> 2, wk = (tid & 3) * 16;
    const float* xg = X + (size_t)(r0 + xr_) * D + xk;
    const float* wg = W + (size_t)(c0 + wr_) * D + wk;
    const int xswz  = (xr_ & 7) << 4;
    const int wswz  = (wr_ & 7) << 4;
    const int xbase = xr_ * 128 + xk * 2;
    const int wbase = wr_ * 128 + wk * 2;

    floatx4 acc[2] = {};
    float4 x0, x1, y0, y1, y2, y3;

#define LDC(k)                                                                  \
    x0 = *(const float4*)(xg + (k));      x1 = *(const float4*)(xg + (k) + 4);  \
    y0 = *(const float4*)(wg + (k));      y1 = *(const float4*)(wg + (k) + 4);  \
    y2 = *(const float4*)(wg + (k) + 8);  y3 = *(const float4*)(wg + (k) + 12);

#define PKC(bi)                                                                 \
    { char* xb = (char*)&Xs[bi][0]; char* wb = (char*)&Wsh[bi][0]; uintx4 q;    \
      q[0] = pack_rne(x0.x, x0.y); q[1] = pack_rne(x0.z, x0.w);                 \
      q[2] = pack_rne(x1.x, x1.y); q[3] = pack_rne(x1.z, x1.w);                 \
      *(uintx4*)(xb + (xbase ^ xswz)) = q;                                      \
      q[0] = pack_rne(y0.x, y0.y); q[1] = pack_rne(y0.z, y0.w);                 \
      q[2] = pack_rne(y1.x, y1.y); q[3] = pack_rne(y1.z, y1.w);                 \
      *(uintx4*)(wb + (wbase ^ wswz)) = q;                                      \
      q[0] = pack_rne(y2.x, y2.y); q[1] = pack_rne(y2.z, y2.w);                 \
      q[2] = pack_rne(y3.x, y3.y); q[3] = pack_rne(y3.z, y3.w);                 \
      *(uintx4*)(wb + ((wbase + 16) ^ wswz)) = q; }

    LDC(0); PKC(0);
    __syncthreads();

    const int asw = (l15 & 7) << 4;
    int cur = 0;
    for (int kc = 0; kc < D; kc += 64) {
        const bool has = (kc + 64) < D;
        if (has) { LDC(kc + 64); }

        const char* xb = (const char*)&Xs[cur][0];
        const char* wb = (const char*)&Wsh[cur][0];
        short8 a0  = *(const short8*)(xb + (((wr + l15) * 128 +      quad * 16) ^ asw));
        short8 a1  = *(const short8*)(xb + (((wr + l15) * 128 + 64 + quad * 16) ^ asw));
        short8 b00 = *(const short8*)(wb + (((wc +      l15) * 128 +      quad * 16) ^ asw));
        short8 b01 = *(const short8*)(wb + (((wc +      l15) * 128 + 64 + quad * 16) ^ asw));
        short8 b10 = *(const short8*)(wb + (((wc + 16 + l15) * 128 +      quad * 16) ^ asw));
        short8 b11 = *(const short8*)(wb + (((wc + 16 + l15) * 128 + 64 + quad * 16) ^ asw));
        acc[0] = MFMA16(a0, b00, acc[0]);
        acc[1] = MFMA16(a0, b10, acc[1]);
        acc[0] = MFMA16(a1, b01, acc[0]);
        acc[1] = MFMA16(a1, b11, acc[1]);

        if (has) { PKC(cur ^ 1); }
        __syncthreads();
        cur ^= 1;
    }
#undef LDC
#undef PKC

    if (is_u) {
#pragma unroll
        for (int tf = 0; tf < 2; tf++)
#pragma unroll
            for (int r = 0; r < 4; r++) {
                const int row = r0 + wr + quad * 4 + r;
                const int col = c0 + wc + tf * 16 + l15;
                upf[(size_t)row * 256 + col] = acc[tf][r];
            }
    } else {
#pragma unroll
        for (int tf = 0; tf < 2; tf++)
#pragma unroll
            for (int r = 0; r < 4; r++) {
                const int row = r0 + wr + quad * 4 + r;
                const int col = c0 + wc + tf * 16 + l15;
                vpb[(size_t)row * 256 + col] = f2bf(acc[tf][r]);
            }
    }
}

// ---------------------------------------------------------------------------
// bilinear v5: A' = vp (.) up in LDS (built once), B = static bf16 Wp from L2,
// barrier-free K-loop, operand-swapped MFMA -> float4 epilogue stores.
// ---------------------------------------------------------------------------
__global__ __launch_bounds__(256) void bilinear_kernel(
    const float* __restrict__ up, const short* __restrict__ vp,
    const short* __restrict__ Wp_bf, const float* __restrict__ bp,
    float* __restrict__ out)
{
    __shared__ __align__(16) short A_lds[128 * 256];   // 64 KB, swizzled
    __shared__ float up_s[256];

    const int tid  = threadIdx.x;
    const int lane = tid & 63;
    const int wave = tid >> 6;
    const int quad = lane >> 4;
    const int l15  = lane & 15;

    // XCD-aware decode: all 64 blocks of one b share bid%8 == b%8.
    const int bid = blockIdx.x;
    const int xcd = bid & 7;
    const int grp = bid >> 3;                 // 0..255
    const int s   = grp & 63;
    const int b   = (grp >> 6) * 8 + xcd;     // 0..31
    const int m   = s >> 1;
    const int f_blk = s & 1;
    const int bm  = b * 32 + m;
    const int f0  = f_blk * 128;
    const int wn  = (wave >> 1) * 64;
    const int wf  = (wave & 1) * 64;

    // ---- stage up row (fp32) ----
    up_s[tid] = up[(size_t)bm * 256 + tid];
    __syncthreads();

    // ---- build A' = vp[b] (.) up into LDS (bf16, XOR-swizzled) ----
    {
        const int jrow = (tid >> 2) * 2;          // 0,2,..,126
        const int kseg = (tid & 3) * 64;          // 0,64,128,192
        const short* vsrc = vp + (size_t)(b * 128 + jrow) * 256 + kseg;
        char* Ab = (char*)A_lds;
#pragma unroll
        for (int i = 0; i < 8; i++) {             // 8 bf16 per step
            const float4 ua = *(const float4*)&up_s[kseg + i * 8];
            const float4 ub = *(const float4*)&up_s[kseg + i * 8 + 4];
#pragma unroll
            for (int r = 0; r < 2; r++) {
                short8 vv = *(const short8*)(vsrc + r * 256 + i * 8);
                uintx4 o;
                o[0] = scale2_rne(vv[0], vv[1], ua.x, ua.y);
                o[1] = scale2_rne(vv[2], vv[3], ua.z, ua.w);
                o[2] = scale2_rne(vv[4], vv[5], ub.x, ub.y);
                o[3] = scale2_rne(vv[6], vv[7], ub.z, ub.w);
                const int row = jrow + r;
                const int byte = (row * 512 + (kseg + i * 8) * 2) ^ ((row & 7) << 4);
                *(uintx4*)(Ab + byte) = o;
            }
        }
    }
    __syncthreads();   // A' ready; NO MORE BARRIERS

    // ---- barrier-free K-loop (operand-swapped: D-rows = f, D-cols = n) ----
    floatx4 acc[4][4] = {};
    const char* Ab = (const char*)A_lds;
    const int aswz = (l15 & 7) << 4;
    const short* wq = Wp_bf + (size_t)(f0 + wf + l15) * 256 + quad * 8;

    short8 bcur[4], bnxt[4];
#pragma unroll
    for (int tt = 0; tt < 4; tt++)
        bcur[tt] = *(const short8*)(wq + tt * 4096);

#pragma unroll
    for (int kc = 0; kc < 256; kc += 32) {
        if (kc < 224) {   // prefetch next chunk's B-frags (L2-hot Wp)
#pragma unroll
            for (int tt = 0; tt < 4; tt++)
                bnxt[tt] = *(const short8*)(wq + tt * 4096 + kc + 32);
        }
        short8 a[4];
#pragma unroll
        for (int tt = 0; tt < 4; tt++) {
            const int row = wn + tt * 16 + l15;
            a[tt] = *(const short8*)(Ab + ((row * 512 + kc * 2 + quad * 16) ^ aswz));
        }
        __builtin_amdgcn_s_setprio(1);
#pragma unroll
        for (int tn = 0; tn < 4; tn++)
#pragma unroll
            for (int tf = 0; tf < 4; tf++)
                acc[tn][tf] = MFMA16(bcur[tf], a[tn], acc[tn][tf]);
        __builtin_amdgcn_s_setprio(0);
        if (kc < 224) {
#pragma unroll
            for (int tt = 0; tt < 4; tt++) bcur[tt] = bnxt[tt];
        }
    }

    // ---- epilogue: f = f0+wf+tf*16+quad*4+r (consecutive in r) ----
    float4 bpv[4];
#pragma unroll
    for (int tf = 0; tf < 4; tf++)
        bpv[tf] = *(const float4*)&bp[f0 + wf + tf * 16 + quad * 4];

    const size_t out_base = (size_t)bm * 128 * 256;
#pragma unroll
    for (int tn = 0; tn < 4; tn++) {
        const int n = wn + tn * 16 + l15;
        float* orow = out + out_base + (size_t)n * 256 + f0 + wf + quad * 4;
#pragma unroll
        for (int tf = 0; tf < 4; tf++) {
            float4 vv;
            vv.x = fmaxf(acc[tn][tf][0] + bpv[tf].x, 0.0f);
            vv.y = fmaxf(acc[tn][tf][1] + bpv[tf].y, 0.0f);
            vv.z = fmaxf(acc[tn][tf][2] + bpv[tf].z, 0.0f);
            vv.w = fmaxf(acc[tn][tf][3] + bpv[tf].w, 0.0f);
            *(float4*)(orow + tf * 16) = vv;
        }
    }
}

extern "C" void kernel_launch(void* const* d_in, const int* in_sizes, int n_in,
                              void* d_out, int out_size, void* d_ws, size_t ws_size,
                              hipStream_t stream) {
    const float* u  = (const float*)d_in[0];   // (32,32,1024)
    const float* v  = (const float*)d_in[1];   // (32,128,2048)
    const float* Wu = (const float*)d_in[2];   // (256,1024)
    const float* Wv = (const float*)d_in[3];   // (256,2048)
    const float* Wp = (const float*)d_in[4];   // (256,256)
    const float* bp = (const float*)d_in[5];   // (256,)
    float* out = (float*)d_out;                // (32,32,128,256)

    float* up_f  = (float*)d_ws;               // 1024*256 fp32
    short* vp_bf = (short*)(up_f + 262144);    // 4096*256 bf16
    short* Wp_bf = vp_bf + 1048576;            // 256*256 bf16

    proj_kernel<<<dim3(640), dim3(256), 0, stream>>>(
        u, Wu, up_f, v, Wv, vp_bf, Wp, Wp_bf);
    bilinear_kernel<<<dim3(2048), dim3(256), 0, stream>>>(
        up_f, vp_bf, Wp_bf, bp, out);
}

// Round 7
// 230.843 us; speedup vs baseline: 1.0633x; 1.0633x over previous
//
#include <hip/hip_runtime.h>
#include <hip/hip_bf16.h>

// LowRankBilinearFusion on MI355X (gfx950) — v6 (resubmit; R6 was an infra flake)
//
//  Diagnosis (R3/R5): bilinear is latency-stall-bound (MfmaUtil 8%, VALU 15%,
//  write BW 25% of peak, conflicts 0) at 2 blocks/CU (64KB LDS). v6 halves the
//  tile to n64 x f256 (A' = 32 KB -> 4 blocks/CU, 16 waves), shortens the
//  serial chain (vp loads issued before barrier 1; 2 barriers total;
//  barrier-free K-loop), writes full 1KB output rows per block.
//
//  1. proj: unchanged (v3 structure): up_f32 = u@Wu^T; vp_bf = v@Wv^T; Wp->bf16.
//  2. bilinear: block = (b, n-half, m): o = relu( (vp (.) up) @ Wp^T + bp ).
//     Wave w owns k-quarter (build) and f-quarter (K-loop). Operand-swapped
//     MFMA -> f on acc regs (float4 stores).

typedef __attribute__((ext_vector_type(8))) short short8;
typedef __attribute__((ext_vector_type(4))) float floatx4;
typedef __attribute__((ext_vector_type(4))) unsigned uintx4;

__device__ __forceinline__ short f2bf(float f) {
    union { float f; unsigned u; } cv; cv.f = f;
    unsigned r = cv.u + 0x7fffu + ((cv.u >> 16) & 1u);
    return (short)(r >> 16);
}
// RNE pack of two fp32 into one dword of two bf16 (lo = x, hi = y).
__device__ __forceinline__ unsigned pack_rne(float x, float y) {
    __hip_bfloat162 h = __float22bfloat162_rn(make_float2(x, y));
    union { __hip_bfloat162 h; unsigned u; } cv; cv.h = h;
    return cv.u;
}
// (bf16 a)*ua, (bf16 b)*ub -> packed bf16 pair, RNE.
__device__ __forceinline__ unsigned scale2_rne(short a, short b, float ua, float ub) {
    float x = __uint_as_float(((unsigned)(unsigned short)a) << 16) * ua;
    float y = __uint_as_float(((unsigned)(unsigned short)b) << 16) * ub;
    return pack_rne(x, y);
}

#define MFMA16(a, b, c) __builtin_amdgcn_mfma_f32_16x16x32_bf16((a), (b), (c), 0, 0, 0)

// ---------------------------------------------------------------------------
// proj: 32x64 tiles. pidx 0..31 -> u (D=1024), 32..159 -> v (D=2048).
// 256 threads = 4 waves (2x2), wave tile 16x32. K-chunk 64. (v3 structure)
// Blocks 0..31 additionally convert Wp fp32 -> bf16 (8 elems/thread).
// ---------------------------------------------------------------------------
__global__ __launch_bounds__(256) void proj_kernel(
    const float* __restrict__ u, const float* __restrict__ Wu,
    float* __restrict__ upf,
    const float* __restrict__ v, const float* __restrict__ Wv,
    short* __restrict__ vpb,
    const float* __restrict__ Wp, short* __restrict__ Wp_bf)
{
    __shared__ __align__(16) short Xs[2][32 * 64];    // 4 KB each
    __shared__ __align__(16) short Wsh[2][64 * 64];   // 8 KB each

    const int tid  = threadIdx.x;
    const int lane = tid & 63;
    const int wave = tid >> 6;
    const int quad = lane >> 4;
    const int l15  = lane & 15;

    const int bid = blockIdx.x;

    // Wp fp32 -> bf16 (65536 elems over blocks 0..31)
    if (bid < 32) {
        const int widx = (bid * 256 + tid) * 8;
        float4 g0 = *(const float4*)(Wp + widx);
        float4 g1 = *(const float4*)(Wp + widx + 4);
        short8 o;
        o[0] = f2bf(g0.x); o[1] = f2bf(g0.y); o[2] = f2bf(g0.z); o[3] = f2bf(g0.w);
        o[4] = f2bf(g1.x); o[5] = f2bf(g1.y); o[6] = f2bf(g1.z); o[7] = f2bf(g1.w);
        *(short8*)(Wp_bf + widx) = o;
    }

    const int xcd = bid & 7, j = bid >> 3;
    const int cb  = j & 3;
    const int pidx = xcd + 8 * (j >> 2);              // 0..159
    const float *X, *W; int D, r0; bool is_u;
    if (pidx < 32) { is_u = true;  X = u; W = Wu; D = 1024; r0 = pidx * 32; }
    else           { is_u = false; X = v; W = Wv; D = 2048; r0 = (pidx - 32) * 32; }
    const int c0 = cb * 64;
    const int wr = (wave >> 1) * 16;                  // 0,16
    const int wc = (wave & 1) * 32;                   // 0,32

    const int xr_ = tid >> 3, xk = (tid & 7) * 8;
    const int wr_ = tid >> 2, wk = (tid & 3) * 16;
    const float* xg = X + (size_t)(r0 + xr_) * D + xk;
    const float* wg = W + (size_t)(c0 + wr_) * D + wk;
    const int xswz  = (xr_ & 7) << 4;
    const int wswz  = (wr_ & 7) << 4;
    const int xbase = xr_ * 128 + xk * 2;
    const int wbase = wr_ * 128 + wk * 2;

    floatx4 acc[2] = {};
    float4 x0, x1, y0, y1, y2, y3;

#define LDC(k)                                                                  \
    x0 = *(const float4*)(xg + (k));      x1 = *(const float4*)(xg + (k) + 4);  \
    y0 = *(const float4*)(wg + (k));      y1 = *(const float4*)(wg + (k) + 4);  \
    y2 = *(const float4*)(wg + (k) + 8);  y3 = *(const float4*)(wg + (k) + 12);

#define PKC(bi)                                                                 \
    { char* xb = (char*)&Xs[bi][0]; char* wb = (char*)&Wsh[bi][0]; uintx4 q;    \
      q[0] = pack_rne(x0.x, x0.y); q[1] = pack_rne(x0.z, x0.w);                 \
      q[2] = pack_rne(x1.x, x1.y); q[3] = pack_rne(x1.z, x1.w);                 \
      *(uintx4*)(xb + (xbase ^ xswz)) = q;                                      \
      q[0] = pack_rne(y0.x, y0.y); q[1] = pack_rne(y0.z, y0.w);                 \
      q[2] = pack_rne(y1.x, y1.y); q[3] = pack_rne(y1.z, y1.w);                 \
      *(uintx4*)(wb + (wbase ^ wswz)) = q;                                      \
      q[0] = pack_rne(y2.x, y2.y); q[1] = pack_rne(y2.z, y2.w);                 \
      q[2] = pack_rne(y3.x, y3.y); q[3] = pack_rne(y3.z, y3.w);                 \
      *(uintx4*)(wb + ((wbase + 16) ^ wswz)) = q; }

    LDC(0); PKC(0);
    __syncthreads();

    const int asw = (l15 & 7) << 4;
    int cur = 0;
    for (int kc = 0; kc < D; kc += 64) {
        const bool has = (kc + 64) < D;
        if (has) { LDC(kc + 64); }

        const char* xb = (const char*)&Xs[cur][0];
        const char* wb = (const char*)&Wsh[cur][0];
        short8 a0  = *(const short8*)(xb + (((wr + l15) * 128 +      quad * 16) ^ asw));
        short8 a1  = *(const short8*)(xb + (((wr + l15) * 128 + 64 + quad * 16) ^ asw));
        short8 b00 = *(const short8*)(wb + (((wc +      l15) * 128 +      quad * 16) ^ asw));
        short8 b01 = *(const short8*)(wb + (((wc +      l15) * 128 + 64 + quad * 16) ^ asw));
        short8 b10 = *(const short8*)(wb + (((wc + 16 + l15) * 128 +      quad * 16) ^ asw));
        short8 b11 = *(const short8*)(wb + (((wc + 16 + l15) * 128 + 64 + quad * 16) ^ asw));
        acc[0] = MFMA16(a0, b00, acc[0]);
        acc[1] = MFMA16(a0, b10, acc[1]);
        acc[0] = MFMA16(a1, b01, acc[0]);
        acc[1] = MFMA16(a1, b11, acc[1]);

        if (has) { PKC(cur ^ 1); }
        __syncthreads();
        cur ^= 1;
    }
#undef LDC
#undef PKC

    if (is_u) {
#pragma unroll
        for (int tf = 0; tf < 2; tf++)
#pragma unroll
            for (int r = 0; r < 4; r++) {
                const int row = r0 + wr + quad * 4 + r;
                const int col = c0 + wc + tf * 16 + l15;
                upf[(size_t)row * 256 + col] = acc[tf][r];
            }
    } else {
#pragma unroll
        for (int tf = 0; tf < 2; tf++)
#pragma unroll
            for (int r = 0; r < 4; r++) {
                const int row = r0 + wr + quad * 4 + r;
                const int col = c0 + wc + tf * 16 + l15;
                vpb[(size_t)row * 256 + col] = f2bf(acc[tf][r]);
            }
    }
}

// ---------------------------------------------------------------------------
// bilinear v6: block = (b, n-half, m); n64 x f256; 32 KB A' LDS; 4 blocks/CU.
// Wave w: builds k-quarter of A' (up_s reads broadcast), owns f-quarter in loop.
// ---------------------------------------------------------------------------
__global__ __launch_bounds__(256, 4) void bilinear_kernel(
    const float* __restrict__ up, const short* __restrict__ vp,
    const short* __restrict__ Wp_bf, const float* __restrict__ bp,
    float* __restrict__ out)
{
    __shared__ __align__(16) short A_lds[64 * 256];   // 32 KB, swizzled
    __shared__ float up_s[256];

    const int tid  = threadIdx.x;
    const int lane = tid & 63;
    const int wave = tid >> 6;
    const int quad = lane >> 4;
    const int l15  = lane & 15;

    // XCD-aware decode: the 64 blocks of one b (2 nhalf x 32 m) share bid%8.
    const int bid = blockIdx.x;
    const int xcd = bid & 7;
    const int grp = bid >> 3;                 // 0..255
    const int s   = grp & 63;
    const int b   = (grp >> 6) * 8 + xcd;     // 0..31
    const int m   = s >> 1;
    const int nh  = s & 1;
    const int bm  = b * 32 + m;

    // stage up row; vp loads issued BEFORE the barrier (latency overlaps)
    up_s[tid] = up[(size_t)bm * 256 + tid];

    const int kw = wave * 64;                 // wave-uniform k-quarter
    const short* vsrc = vp + (size_t)(b * 128 + nh * 64 + lane) * 256 + kw;
    short8 vv[8];
#pragma unroll
    for (int i = 0; i < 8; i++) vv[i] = *(const short8*)(vsrc + i * 8);

    __syncthreads();                          // up_s ready

    // build A' = vp (.) up (rows = lane, cols = kw..kw+63), XOR-swizzled
    {
        char* Ab = (char*)A_lds;
        const int rsw   = (lane & 7) << 4;
        const int rbase = lane * 512 + kw * 2;
#pragma unroll
        for (int i = 0; i < 8; i++) {
            const float4 ua = *(const float4*)&up_s[kw + i * 8];      // broadcast
            const float4 ub = *(const float4*)&up_s[kw + i * 8 + 4];  // broadcast
            uintx4 o;
            o[0] = scale2_rne(vv[i][0], vv[i][1], ua.x, ua.y);
            o[1] = scale2_rne(vv[i][2], vv[i][3], ua.z, ua.w);
            o[2] = scale2_rne(vv[i][4], vv[i][5], ub.x, ub.y);
            o[3] = scale2_rne(vv[i][6], vv[i][7], ub.z, ub.w);
            *(uintx4*)(Ab + ((rbase + i * 16) ^ rsw)) = o;
        }
    }
    __syncthreads();                          // A' ready; NO MORE BARRIERS

    // barrier-free K-loop (operand-swapped: D-rows = f, D-cols = n)
    floatx4 acc[4][4] = {};
    const char* Ab = (const char*)A_lds;
    const int aswz = (l15 & 7) << 4;
    const int wf   = wave * 64;               // wave-uniform f-quarter
    const short* wq = Wp_bf + (size_t)(wf + l15) * 256 + quad * 8;

    short8 bcur[4], bnxt[4];
#pragma unroll
    for (int tt = 0; tt < 4; tt++)
        bcur[tt] = *(const short8*)(wq + tt * 4096);

#pragma unroll
    for (int kc = 0; kc < 256; kc += 32) {
        if (kc < 224) {   // prefetch next chunk's B-frags (L2-hot Wp)
#pragma unroll
            for (int tt = 0; tt < 4; tt++)
                bnxt[tt] = *(const short8*)(wq + tt * 4096 + kc + 32);
        }
        short8 a[4];
#pragma unroll
        for (int tt = 0; tt < 4; tt++) {
            const int row = tt * 16 + l15;    // n-rows 0..63
            a[tt] = *(const short8*)(Ab + ((row * 512 + kc * 2 + quad * 16) ^ aswz));
        }
        __builtin_amdgcn_s_setprio(1);
#pragma unroll
        for (int tn = 0; tn < 4; tn++)
#pragma unroll
            for (int tf = 0; tf < 4; tf++)
                acc[tn][tf] = MFMA16(bcur[tf], a[tn], acc[tn][tf]);
        __builtin_amdgcn_s_setprio(0);
        if (kc < 224) {
#pragma unroll
            for (int tt = 0; tt < 4; tt++) bcur[tt] = bnxt[tt];
        }
    }

    // epilogue: f = wf + tf*16 + quad*4 + r (consecutive in r); n = tn*16+l15
    float4 bpv[4];
#pragma unroll
    for (int tf = 0; tf < 4; tf++)
        bpv[tf] = *(const float4*)&bp[wf + tf * 16 + quad * 4];

    const size_t out_base = (size_t)bm * 128 * 256 + (size_t)nh * 64 * 256;
#pragma unroll
    for (int tn = 0; tn < 4; tn++) {
        const int n = tn * 16 + l15;
        float* orow = out + out_base + (size_t)n * 256 + wf + quad * 4;
#pragma unroll
        for (int tf = 0; tf < 4; tf++) {
            float4 vo;
            vo.x = fmaxf(acc[tn][tf][0] + bpv[tf].x, 0.0f);
            vo.y = fmaxf(acc[tn][tf][1] + bpv[tf].y, 0.0f);
            vo.z = fmaxf(acc[tn][tf][2] + bpv[tf].z, 0.0f);
            vo.w = fmaxf(acc[tn][tf][3] + bpv[tf].w, 0.0f);
            *(float4*)(orow + tf * 16) = vo;
        }
    }
}

extern "C" void kernel_launch(void* const* d_in, const int* in_sizes, int n_in,
                              void* d_out, int out_size, void* d_ws, size_t ws_size,
                              hipStream_t stream) {
    const float* u  = (const float*)d_in[0];   // (32,32,1024)
    const float* v  = (const float*)d_in[1];   // (32,128,2048)
    const float* Wu = (const float*)d_in[2];   // (256,1024)
    const float* Wv = (const float*)d_in[3];   // (256,2048)
    const float* Wp = (const float*)d_in[4];   // (256,256)
    const float* bp = (const float*)d_in[5];   // (256,)
    float* out = (float*)d_out;                // (32,32,128,256)

    float* up_f  = (float*)d_ws;               // 1024*256 fp32
    short* vp_bf = (short*)(up_f + 262144);    // 4096*256 bf16
    short* Wp_bf = vp_bf + 1048576;            // 256*256 bf16

    proj_kernel<<<dim3(640), dim3(256), 0, stream>>>(
        u, Wu, up_f, v, Wv, vp_bf, Wp, Wp_bf);
    bilinear_kernel<<<dim3(2048), dim3(256), 0, stream>>>(
        up_f, vp_bf, Wp_bf, bp, out);
}